// Round 3
// baseline (536.629 us; speedup 1.0000x reference)
//
#include <hip/hip_runtime.h>
#include <hip/hip_bf16.h>

// B=4, L=4096, D=1024, H=16, M=4, dk=64, n=1024. All-bf16 MFMA pipeline.
// R3: gemm_k LDS re-laid out frag-packed ([rt8][ks][g][c][8]) so every MFMA
// fragment load is a lane-linear contiguous ds_read_b128 (zero bank conflicts).
// R2 had row-stride 128B = 32 banks -> 16-way conflicts = ~34% of gemm cycles.

typedef __attribute__((ext_vector_type(8))) short short8;
typedef __attribute__((ext_vector_type(8))) unsigned short ushort8v;
typedef __attribute__((ext_vector_type(4))) float floatx4;

__device__ __forceinline__ float b2f(unsigned short h) {
    union { unsigned int u; float f; } v; v.u = ((unsigned int)h) << 16; return v.f;
}
__device__ __forceinline__ unsigned short f2b(float f) {
    union { float f; unsigned int u; } v; v.f = f;
    unsigned int r = v.u + 0x7fffu + ((v.u >> 16) & 1u);
    return (unsigned short)(r >> 16);
}
// pack two non-negative floats to bf16 pair (round-half-up; inputs are exp2 outputs >= 0)
__device__ __forceinline__ unsigned int pack2bf(float lo, float hi) {
    union { float f; unsigned int u; } a, b; a.f = lo; b.f = hi;
    return ((b.u + 0x8000u) & 0xFFFF0000u) | (((a.u + 0x8000u) >> 16) & 0xFFFFu);
}
__device__ __forceinline__ void async_copy16(const unsigned short* g, unsigned short* l) {
    __builtin_amdgcn_global_load_lds((const __attribute__((address_space(1))) void*)g,
                                     (__attribute__((address_space(3))) void*)l, 16, 0, 0);
}

// ---------------- fp32 -> bf16 convert (x) ----------------
__global__ __launch_bounds__(256)
void cvt_kernel(const float* __restrict__ in, unsigned short* __restrict__ out, int n4) {
    int i = blockIdx.x * 256 + threadIdx.x;
    if (i >= n4) return;
    float4 v = ((const float4*)in)[i];
    ushort4 o;
    o.x = f2b(v.x); o.y = f2b(v.y); o.z = f2b(v.z); o.w = f2b(v.w);
    ((ushort4*)out)[i] = o;
}

// ---------------- W [K][N] fp32 -> Wt [N][K] bf16 (optionally scaled) ----------------
__global__ __launch_bounds__(256)
void cvt_w_t(const float* __restrict__ W, unsigned short* __restrict__ Wt, float sc) {
    __shared__ float tile[64][65];
    const int kt = blockIdx.x, nt = blockIdx.y;
    const int t = threadIdx.x;
    const int r = t >> 2, cg = t & 3;
    const float* src = W + (size_t)(kt * 64 + r) * 1024 + nt * 64 + cg * 16;
#pragma unroll
    for (int j = 0; j < 4; j++) {
        float4 v = *(const float4*)(src + j * 4);
        tile[r][cg * 16 + j * 4 + 0] = v.x;
        tile[r][cg * 16 + j * 4 + 1] = v.y;
        tile[r][cg * 16 + j * 4 + 2] = v.z;
        tile[r][cg * 16 + j * 4 + 3] = v.w;
    }
    __syncthreads();
    unsigned short* dst = Wt + (size_t)(nt * 64 + r) * 1024 + kt * 64 + cg * 16;
    ushort8v o0, o1;
#pragma unroll
    for (int j = 0; j < 8; j++) o0[j] = f2b(tile[cg * 16 + j][r] * sc);
#pragma unroll
    for (int j = 0; j < 8; j++) o1[j] = f2b(tile[cg * 16 + 8 + j][r] * sc);
    *(ushort8v*)(dst) = o0;
    *(ushort8v*)(dst + 8) = o1;
}

// ---------------- GEMM: C[M][N] = A[M][K] * Bt[N][K]^T + bias*bs ----------------
// 128x128 tile, BK=64, 4 waves (2x2), 4x4 16x16x32 MFMA per wave.
// LDS frag-packed: elem(((rt8*2+ks)*4+g)*16+c)*8+j  ->  read = base + lane*8.
template <bool F32OUT>
__global__ __launch_bounds__(256)
void gemm_k(const unsigned short* __restrict__ A,
            const unsigned short* __restrict__ BtBase,
            const float* __restrict__ bias0,
            const float* __restrict__ bias1,
            const float* __restrict__ bias2,
            void* __restrict__ OutBase, float s0) {
    constexpr int K = 1024, N = 1024;
    __shared__ __align__(16) unsigned short As[128 * 64];
    __shared__ __align__(16) unsigned short Bs[128 * 64];
    const int z = blockIdx.z;
    const unsigned short* Bt = BtBase + (size_t)z * (1024 * 1024);
    const float* bias = (z == 0) ? bias0 : (z == 1 ? bias1 : bias2);
    const float bs = (z == 0) ? s0 : 1.0f;
    const int tileN = blockIdx.x, tileM = blockIdx.y;
    const int tid = threadIdx.x, w = tid >> 6, lane = tid & 63;
    const int wr = w >> 1, wc = w & 1;
    const int g = lane >> 4, c = lane & 15;

    floatx4 acc[4][4];
#pragma unroll
    for (int i = 0; i < 4; i++)
#pragma unroll
        for (int j = 0; j < 4; j++) acc[i][j] = (floatx4){0.f, 0.f, 0.f, 0.f};

    for (int kt = 0; kt < K / 64; ++kt) {
        __syncthreads();
        // stage frag-packed: copy seg covers 16 rows x 8 k-elems (lane=g*16+c
        // loads row rt8*16+c, chunk ks*32+g*8); LDS dest is wave-uniform base.
#pragma unroll
        for (int t = 0; t < 4; t++) {
            int seg = w * 4 + t;          // 0..15
            int rt8 = seg >> 1, ks = seg & 1;
            int rowA = tileM * 128 + rt8 * 16 + c;
            async_copy16(A + (size_t)rowA * K + kt * 64 + ks * 32 + g * 8, As + seg * 512);
            int rowB = tileN * 128 + rt8 * 16 + c;
            async_copy16(Bt + (size_t)rowB * K + kt * 64 + ks * 32 + g * 8, Bs + seg * 512);
        }
        __syncthreads();
#pragma unroll
        for (int ks = 0; ks < 2; ks++) {
            short8 af[4], bf[4];
#pragma unroll
            for (int rt = 0; rt < 4; rt++)
                af[rt] = *(const short8*)(As + ((wr * 4 + rt) * 2 + ks) * 512 + lane * 8);
#pragma unroll
            for (int ct = 0; ct < 4; ct++)
                bf[ct] = *(const short8*)(Bs + ((wc * 4 + ct) * 2 + ks) * 512 + lane * 8);
#pragma unroll
            for (int rt = 0; rt < 4; rt++)
#pragma unroll
                for (int ct = 0; ct < 4; ct++)
                    acc[rt][ct] = __builtin_amdgcn_mfma_f32_16x16x32_bf16(af[rt], bf[ct], acc[rt][ct], 0, 0, 0);
        }
    }
#pragma unroll
    for (int ct = 0; ct < 4; ct++) {
        int col = tileN * 128 + wc * 64 + ct * 16 + c;
        float bvv = bias[col] * bs;
#pragma unroll
        for (int rt = 0; rt < 4; rt++) {
            int row0 = tileM * 128 + wr * 64 + rt * 16 + g * 4;
#pragma unroll
            for (int r = 0; r < 4; r++) {
                float v = acc[rt][ct][r] + bvv;
                if (F32OUT) {
                    ((float*)OutBase)[(size_t)(row0 + r) * N + col] = v;
                } else {
                    ((unsigned short*)OutBase)[(size_t)z * (16384ull * 1024ull) +
                                               (size_t)(row0 + r) * N + col] = f2b(v);
                }
            }
        }
    }
}

// ---------------- V transpose: v[B,L,D] -> Vt[slice=(b,h,m)][d=64][i=1024] ----------------
__global__ __launch_bounds__(256)
void vtrans(const unsigned short* __restrict__ V, unsigned short* __restrict__ Vt) {
    __shared__ unsigned short tile[64 * 72];
    const int it = blockIdx.x, s = blockIdx.y;
    const int m = s & 3, h = (s >> 2) & 15, b = s >> 6;
    const int tid = threadIdx.x;
    {
        int il = tid >> 2, cg = tid & 3;
        const unsigned short* gsrc =
            V + ((size_t)b * 4096 + m + 4 * (it * 64 + il)) * 1024 + h * 64 + cg * 16;
        *(ushort8v*)(tile + il * 72 + cg * 16) = *(const ushort8v*)gsrc;
        *(ushort8v*)(tile + il * 72 + cg * 16 + 8) = *(const ushort8v*)(gsrc + 8);
    }
    __syncthreads();
    {
        int dl = tid >> 2, ig = (tid & 3) * 16;
        ushort8v o0, o1;
#pragma unroll
        for (int j = 0; j < 8; j++) o0[j] = tile[(ig + j) * 72 + dl];
#pragma unroll
        for (int j = 0; j < 8; j++) o1[j] = tile[(ig + 8 + j) * 72 + dl];
        unsigned short* dst = Vt + (size_t)s * 65536 + (size_t)dl * 1024 + it * 64 + ig;
        *(ushort8v*)dst = o0;
        *(ushort8v*)(dst + 8) = o1;
    }
}

// ---------------- Attention ----------------
// grid (8 qtiles, 256 slices), 256 threads = 4 waves, 32 q-rows/wave.
// S^T = K·Q^T (both natural), softmax without max-sub (scores tiny; scale folded
// into Wq as 0.125*log2e), P packed b64 into per-wave LDS, O = P·V (V^T staged).
__global__ __launch_bounds__(256)
void attn_k(const unsigned short* __restrict__ Qg,
            const unsigned short* __restrict__ Kg,
            const unsigned short* __restrict__ Vt,
            unsigned short* __restrict__ Og) {
    __shared__ __align__(16) unsigned short Qs[128 * 64];   // [w][rt][ks][g][c][8]
    __shared__ __align__(16) unsigned short Ks[64 * 64];    // [kt4][ks][g][c][8]
    __shared__ __align__(16) unsigned short Vs[64 * 64];    // [dt][kc][g][c][8]
    __shared__ __align__(16) unsigned short Ps[4 * 2048];   // per-wave [rt*2+kc][g][c][8]
    __shared__ float als[128];

    const int qt = blockIdx.x;
    const int s = blockIdx.y;
    const int m = s & 3, h = (s >> 2) & 15, b = s >> 6;
    const int tid = threadIdx.x, w = tid >> 6, lane = tid & 63;
    const int g = lane >> 4, c = lane & 15;
    const size_t rowBase = (size_t)b * 4096;
    const unsigned short* VtS = Vt + (size_t)s * 65536;

    // stage Q (already scaled via Wq fold): 4 async copies per wave
#pragma unroll
    for (int rt = 0; rt < 2; rt++)
#pragma unroll
        for (int ks = 0; ks < 2; ks++) {
            int token = m + 4 * (qt * 128 + w * 32 + rt * 16 + c);
            async_copy16(Qg + (rowBase + token) * 1024 + h * 64 + ks * 32 + g * 8,
                         Qs + ((w * 2 + rt) * 2 + ks) * 512);
        }

    floatx4 oacc[2][4];
#pragma unroll
    for (int rt = 0; rt < 2; rt++)
#pragma unroll
        for (int dt = 0; dt < 4; dt++) oacc[rt][dt] = (floatx4){0.f, 0.f, 0.f, 0.f};
    float lsum[2] = {0.f, 0.f};

    for (int kt = 0; kt < 16; ++kt) {
        __syncthreads();
        // stage K tile (keys kt*64..+64): wave w handles key sub-tile kt4=w
#pragma unroll
        for (int ks = 0; ks < 2; ks++) {
            int token = m + 4 * (kt * 64 + w * 16 + c);
            async_copy16(Kg + (rowBase + token) * 1024 + h * 64 + ks * 32 + g * 8,
                         Ks + (w * 2 + ks) * 512);
        }
        // stage V^T tile: wave w handles d sub-tile dt=w
#pragma unroll
        for (int kc = 0; kc < 2; kc++) {
            async_copy16(VtS + (size_t)(w * 16 + c) * 1024 + kt * 64 + kc * 32 + g * 8,
                         Vs + (w * 2 + kc) * 512);
        }
        __syncthreads();

        // S^T[key][q] = K·Q^T : A=K (4 key-tiles), B=Q (2 q-tiles)
        floatx4 sacc[4][2];
#pragma unroll
        for (int k4 = 0; k4 < 4; k4++)
#pragma unroll
            for (int rt = 0; rt < 2; rt++) sacc[k4][rt] = (floatx4){0.f, 0.f, 0.f, 0.f};
#pragma unroll
        for (int ks = 0; ks < 2; ks++) {
            short8 kf[4], qf[2];
#pragma unroll
            for (int k4 = 0; k4 < 4; k4++)
                kf[k4] = *(const short8*)(Ks + (((k4 * 2 + ks) * 4 + g) * 16 + c) * 8);
#pragma unroll
            for (int rt = 0; rt < 2; rt++)
                qf[rt] = *(const short8*)(Qs + ((((w * 2 + rt) * 2 + ks) * 4 + g) * 16 + c) * 8);
#pragma unroll
            for (int k4 = 0; k4 < 4; k4++)
#pragma unroll
                for (int rt = 0; rt < 2; rt++)
                    sacc[k4][rt] = __builtin_amdgcn_mfma_f32_16x16x32_bf16(kf[k4], qf[rt], sacc[k4][rt], 0, 0, 0);
        }

        // p = exp2(s) (no max-sub), accumulate l partials, pack -> Ps (per-wave)
#pragma unroll
        for (int k4 = 0; k4 < 4; k4++) {
            const int kc = k4 >> 1;
            const int gr = (k4 & 1) * 2 + (g >> 1);
            const int j0 = (g & 1) * 4;
#pragma unroll
            for (int rt = 0; rt < 2; rt++) {
                float e0 = __builtin_amdgcn_exp2f(sacc[k4][rt][0]);
                float e1 = __builtin_amdgcn_exp2f(sacc[k4][rt][1]);
                float e2 = __builtin_amdgcn_exp2f(sacc[k4][rt][2]);
                float e3 = __builtin_amdgcn_exp2f(sacc[k4][rt][3]);
                lsum[rt] += (e0 + e1) + (e2 + e3);
                uint2 pk;
                pk.x = pack2bf(e0, e1);
                pk.y = pack2bf(e2, e3);
                *(uint2*)(Ps + w * 2048 + (((rt * 2 + kc) * 4 + gr) * 16 + c) * 8 + j0) = pk;
            }
        }

        // O += P·V : A=P (2 q-tiles), B=V^T (4 d-tiles), K=64 keys (2 chunks)
#pragma unroll
        for (int kc = 0; kc < 2; kc++) {
            short8 pf[2], vf[4];
#pragma unroll
            for (int rt = 0; rt < 2; rt++)
                pf[rt] = *(const short8*)(Ps + w * 2048 + (((rt * 2 + kc) * 4 + g) * 16 + c) * 8);
#pragma unroll
            for (int dt = 0; dt < 4; dt++)
                vf[dt] = *(const short8*)(Vs + (((dt * 2 + kc) * 4 + g) * 16 + c) * 8);
#pragma unroll
            for (int rt = 0; rt < 2; rt++)
#pragma unroll
                for (int dt = 0; dt < 4; dt++)
                    oacc[rt][dt] = __builtin_amdgcn_mfma_f32_16x16x32_bf16(pf[rt], vf[dt], oacc[rt][dt], 0, 0, 0);
        }
    }

    // final l reduce across g-groups (lanes differing by 16/32), broadcast 1/l via LDS
#pragma unroll
    for (int rt = 0; rt < 2; rt++) {
        float l = lsum[rt];
        l += __shfl_xor(l, 16, 64);
        l += __shfl_xor(l, 32, 64);
        if (lane < 16) als[w * 32 + rt * 16 + c] = 1.0f / l;
    }
    float4 li[2];
#pragma unroll
    for (int rt = 0; rt < 2; rt++) li[rt] = *(float4*)(&als[w * 32 + rt * 16 + g * 4]);

#pragma unroll
    for (int rt = 0; rt < 2; rt++) {
#pragma unroll
        for (int r = 0; r < 4; r++) {
            float inv = (r == 0) ? li[rt].x : (r == 1) ? li[rt].y : (r == 2) ? li[rt].z : li[rt].w;
            int token = m + 4 * (qt * 128 + w * 32 + rt * 16 + g * 4 + r);
            size_t rowOff = (rowBase + token) * 1024 + h * 64;
#pragma unroll
            for (int dt = 0; dt < 4; dt++)
                Og[rowOff + dt * 16 + c] = f2b(oacc[rt][dt][r] * inv);
        }
    }
}

extern "C" void kernel_launch(void* const* d_in, const int* in_sizes, int n_in,
                              void* d_out, int out_size, void* d_ws, size_t ws_size,
                              hipStream_t stream) {
    const float* x  = (const float*)d_in[0];
    const float* Wq = (const float*)d_in[1];
    const float* bq = (const float*)d_in[2];
    const float* Wk = (const float*)d_in[3];
    const float* bk = (const float*)d_in[4];
    const float* Wv = (const float*)d_in[5];
    const float* bv = (const float*)d_in[6];
    const float* Wo = (const float*)d_in[7];
    const float* bo = (const float*)d_in[8];

    const float SC = 0.18033688011112042f;  // (1/8) * log2(e), folded into Wq/bq

    char* ws = (char*)d_ws;
    const size_t SZ = 33554432;  // 32 MB = 16M bf16
    unsigned short* xb  = (unsigned short*)(ws);          // dead after QKV gemm
    unsigned short* Vtp = (unsigned short*)(ws);          // reuses xb region
    unsigned short* qb  = (unsigned short*)(ws + SZ);     // q,k,v contiguous
    unsigned short* ob  = (unsigned short*)(ws + 4 * SZ);
    unsigned short* Wt3 = (unsigned short*)(ws + 5 * SZ);
    unsigned short* Wot = Wt3 + 3ull * 1024 * 1024;

    cvt_kernel<<<16384, 256, 0, stream>>>(x, xb, 4194304);
    cvt_w_t<<<dim3(16, 16), 256, 0, stream>>>(Wq, Wt3, SC);
    cvt_w_t<<<dim3(16, 16), 256, 0, stream>>>(Wk, Wt3 + 1048576, 1.0f);
    cvt_w_t<<<dim3(16, 16), 256, 0, stream>>>(Wv, Wt3 + 2097152, 1.0f);
    cvt_w_t<<<dim3(16, 16), 256, 0, stream>>>(Wo, Wot, 1.0f);
    gemm_k<false><<<dim3(8, 128, 3), 256, 0, stream>>>(xb, Wt3, bq, bk, bv, qb, SC);
    vtrans<<<dim3(16, 256), 256, 0, stream>>>(qb + 2ull * 16777216ull, Vtp);
    attn_k<<<dim3(8, 256), 256, 0, stream>>>(qb, qb + 16777216ull, Vtp, ob);
    gemm_k<true><<<dim3(8, 128, 1), 256, 0, stream>>>(ob, Wot, bo, bo, bo, d_out, 1.0f);
}

// Round 4
// 464.213 us; speedup vs baseline: 1.1560x; 1.1560x over previous
//
#include <hip/hip_runtime.h>
#include <hip/hip_bf16.h>

// B=4, L=4096, D=1024, H=16, M=4, dk=64, n=1024. All-bf16 MFMA pipeline.
// R4: gemm_k XOR-swizzled LDS — staging keeps 8-row x 128B full-line global
// segments (R2 speed) while chunk (row,kc) lands at row*8 + (kc^(row&7)),
// making frag reads 2-way-aliased max (free, m136). R3's lane-linear layout
// had 0 conflicts but 16-row x 64B half-line staging throttled VMEM.

typedef __attribute__((ext_vector_type(8))) short short8;
typedef __attribute__((ext_vector_type(8))) unsigned short ushort8v;
typedef __attribute__((ext_vector_type(4))) float floatx4;

__device__ __forceinline__ float b2f(unsigned short h) {
    union { unsigned int u; float f; } v; v.u = ((unsigned int)h) << 16; return v.f;
}
__device__ __forceinline__ unsigned short f2b(float f) {
    union { float f; unsigned int u; } v; v.f = f;
    unsigned int r = v.u + 0x7fffu + ((v.u >> 16) & 1u);
    return (unsigned short)(r >> 16);
}
// pack two non-negative floats to bf16 pair (round-half-up; inputs are exp2 outputs >= 0)
__device__ __forceinline__ unsigned int pack2bf(float lo, float hi) {
    union { float f; unsigned int u; } a, b; a.f = lo; b.f = hi;
    return ((b.u + 0x8000u) & 0xFFFF0000u) | (((a.u + 0x8000u) >> 16) & 0xFFFFu);
}
__device__ __forceinline__ void async_copy16(const unsigned short* g, unsigned short* l) {
    __builtin_amdgcn_global_load_lds((const __attribute__((address_space(1))) void*)g,
                                     (__attribute__((address_space(3))) void*)l, 16, 0, 0);
}

// ---------------- fp32 -> bf16 convert (x) ----------------
__global__ __launch_bounds__(256)
void cvt_kernel(const float* __restrict__ in, unsigned short* __restrict__ out, int n4) {
    int i = blockIdx.x * 256 + threadIdx.x;
    if (i >= n4) return;
    float4 v = ((const float4*)in)[i];
    ushort4 o;
    o.x = f2b(v.x); o.y = f2b(v.y); o.z = f2b(v.z); o.w = f2b(v.w);
    ((ushort4*)out)[i] = o;
}

// ---------------- W [K][N] fp32 -> Wt [N][K] bf16 (optionally scaled) ----------------
__global__ __launch_bounds__(256)
void cvt_w_t(const float* __restrict__ W, unsigned short* __restrict__ Wt, float sc) {
    __shared__ float tile[64][65];
    const int kt = blockIdx.x, nt = blockIdx.y;
    const int t = threadIdx.x;
    const int r = t >> 2, cg = t & 3;
    const float* src = W + (size_t)(kt * 64 + r) * 1024 + nt * 64 + cg * 16;
#pragma unroll
    for (int j = 0; j < 4; j++) {
        float4 v = *(const float4*)(src + j * 4);
        tile[r][cg * 16 + j * 4 + 0] = v.x;
        tile[r][cg * 16 + j * 4 + 1] = v.y;
        tile[r][cg * 16 + j * 4 + 2] = v.z;
        tile[r][cg * 16 + j * 4 + 3] = v.w;
    }
    __syncthreads();
    unsigned short* dst = Wt + (size_t)(nt * 64 + r) * 1024 + kt * 64 + cg * 16;
    ushort8v o0, o1;
#pragma unroll
    for (int j = 0; j < 8; j++) o0[j] = f2b(tile[cg * 16 + j][r] * sc);
#pragma unroll
    for (int j = 0; j < 8; j++) o1[j] = f2b(tile[cg * 16 + 8 + j][r] * sc);
    *(ushort8v*)(dst) = o0;
    *(ushort8v*)(dst + 8) = o1;
}

// ---------------- GEMM: C[M][N] = A[M][K] * Bt[N][K]^T + bias*bs ----------------
// 128x128 tile, BK=64, 4 waves (2x2), 4x4 16x16x32 MFMA per wave.
// LDS: chunk(row,kc) @ elem (row*8 + (kc^(row&7)))*8. Staging lane l=(r8,j):
// row=seg*8+r8, kc=j^r8 -> full 128B/row global segments, lane-linear LDS dest.
template <bool F32OUT>
__global__ __launch_bounds__(256)
void gemm_k(const unsigned short* __restrict__ A,
            const unsigned short* __restrict__ BtBase,
            const float* __restrict__ bias0,
            const float* __restrict__ bias1,
            const float* __restrict__ bias2,
            void* __restrict__ OutBase, float s0) {
    constexpr int K = 1024, N = 1024;
    __shared__ __align__(16) unsigned short As[128 * 64];
    __shared__ __align__(16) unsigned short Bs[128 * 64];
    const int z = blockIdx.z;
    const unsigned short* Bt = BtBase + (size_t)z * (1024 * 1024);
    const float* bias = (z == 0) ? bias0 : (z == 1 ? bias1 : bias2);
    const float bs = (z == 0) ? s0 : 1.0f;
    const int tileN = blockIdx.x, tileM = blockIdx.y;
    const int tid = threadIdx.x, w = tid >> 6, lane = tid & 63;
    const int wr = w >> 1, wc = w & 1;
    const int g = lane >> 4, c = lane & 15;
    const int c7 = c & 7;
    const int r8 = lane >> 3, j8 = lane & 7;
    const int kcs = (j8 ^ r8) * 8;   // swizzled k-chunk this lane stages

    floatx4 acc[4][4];
#pragma unroll
    for (int i = 0; i < 4; i++)
#pragma unroll
        for (int jj = 0; jj < 4; jj++) acc[i][jj] = (floatx4){0.f, 0.f, 0.f, 0.f};

    for (int kt = 0; kt < K / 64; ++kt) {
        __syncthreads();
#pragma unroll
        for (int t = 0; t < 4; t++) {
            int seg = w * 4 + t;                 // 0..15, covers rows seg*8..+7
            int rowA = tileM * 128 + seg * 8 + r8;
            async_copy16(A + (size_t)rowA * K + kt * 64 + kcs, As + seg * 512);
            int rowB = tileN * 128 + seg * 8 + r8;
            async_copy16(Bt + (size_t)rowB * K + kt * 64 + kcs, Bs + seg * 512);
        }
        __syncthreads();
#pragma unroll
        for (int ks = 0; ks < 2; ks++) {
            short8 af[4], bf[4];
            const int kx = ((ks * 4 + g) ^ c7) * 8;  // swizzled chunk offset for read
#pragma unroll
            for (int rt = 0; rt < 4; rt++)
                af[rt] = *(const short8*)(As + (wr * 64 + rt * 16 + c) * 64 + kx);
#pragma unroll
            for (int ct = 0; ct < 4; ct++)
                bf[ct] = *(const short8*)(Bs + (wc * 64 + ct * 16 + c) * 64 + kx);
#pragma unroll
            for (int rt = 0; rt < 4; rt++)
#pragma unroll
                for (int ct = 0; ct < 4; ct++)
                    acc[rt][ct] = __builtin_amdgcn_mfma_f32_16x16x32_bf16(af[rt], bf[ct], acc[rt][ct], 0, 0, 0);
        }
    }
#pragma unroll
    for (int ct = 0; ct < 4; ct++) {
        int col = tileN * 128 + wc * 64 + ct * 16 + c;
        float bvv = bias[col] * bs;
#pragma unroll
        for (int rt = 0; rt < 4; rt++) {
            int row0 = tileM * 128 + wr * 64 + rt * 16 + g * 4;
#pragma unroll
            for (int r = 0; r < 4; r++) {
                float v = acc[rt][ct][r] + bvv;
                if (F32OUT) {
                    ((float*)OutBase)[(size_t)(row0 + r) * N + col] = v;
                } else {
                    ((unsigned short*)OutBase)[(size_t)z * (16384ull * 1024ull) +
                                               (size_t)(row0 + r) * N + col] = f2b(v);
                }
            }
        }
    }
}

// ---------------- V transpose: v[B,L,D] -> Vt[slice=(b,h,m)][d=64][i=1024] ----------------
__global__ __launch_bounds__(256)
void vtrans(const unsigned short* __restrict__ V, unsigned short* __restrict__ Vt) {
    __shared__ unsigned short tile[64 * 72];
    const int it = blockIdx.x, s = blockIdx.y;
    const int m = s & 3, h = (s >> 2) & 15, b = s >> 6;
    const int tid = threadIdx.x;
    {
        int il = tid >> 2, cg = tid & 3;
        const unsigned short* gsrc =
            V + ((size_t)b * 4096 + m + 4 * (it * 64 + il)) * 1024 + h * 64 + cg * 16;
        *(ushort8v*)(tile + il * 72 + cg * 16) = *(const ushort8v*)gsrc;
        *(ushort8v*)(tile + il * 72 + cg * 16 + 8) = *(const ushort8v*)(gsrc + 8);
    }
    __syncthreads();
    {
        int dl = tid >> 2, ig = (tid & 3) * 16;
        ushort8v o0, o1;
#pragma unroll
        for (int j = 0; j < 8; j++) o0[j] = tile[(ig + j) * 72 + dl];
#pragma unroll
        for (int j = 0; j < 8; j++) o1[j] = tile[(ig + 8 + j) * 72 + dl];
        unsigned short* dst = Vt + (size_t)s * 65536 + (size_t)dl * 1024 + it * 64 + ig;
        *(ushort8v*)dst = o0;
        *(ushort8v*)(dst + 8) = o1;
    }
}

// ---------------- Attention ----------------
// grid (8 qtiles, 256 slices), 256 threads = 4 waves, 32 q-rows/wave.
// S^T = K·Q^T (both natural), softmax without max-sub (scores tiny; scale folded
// into Wq as 0.125*log2e), P packed b64 into per-wave LDS, O = P·V (V^T staged).
__global__ __launch_bounds__(256)
void attn_k(const unsigned short* __restrict__ Qg,
            const unsigned short* __restrict__ Kg,
            const unsigned short* __restrict__ Vt,
            unsigned short* __restrict__ Og) {
    __shared__ __align__(16) unsigned short Qs[128 * 64];   // [w][rt][ks][g][c][8]
    __shared__ __align__(16) unsigned short Ks[64 * 64];    // [kt4][ks][g][c][8]
    __shared__ __align__(16) unsigned short Vs[64 * 64];    // [dt][kc][g][c][8]
    __shared__ __align__(16) unsigned short Ps[4 * 2048];   // per-wave [rt*2+kc][g][c][8]
    __shared__ float als[128];

    const int qt = blockIdx.x;
    const int s = blockIdx.y;
    const int m = s & 3, h = (s >> 2) & 15, b = s >> 6;
    const int tid = threadIdx.x, w = tid >> 6, lane = tid & 63;
    const int g = lane >> 4, c = lane & 15;
    const size_t rowBase = (size_t)b * 4096;
    const unsigned short* VtS = Vt + (size_t)s * 65536;

    // stage Q (already scaled via Wq fold): 4 async copies per wave
#pragma unroll
    for (int rt = 0; rt < 2; rt++)
#pragma unroll
        for (int ks = 0; ks < 2; ks++) {
            int token = m + 4 * (qt * 128 + w * 32 + rt * 16 + c);
            async_copy16(Qg + (rowBase + token) * 1024 + h * 64 + ks * 32 + g * 8,
                         Qs + ((w * 2 + rt) * 2 + ks) * 512);
        }

    floatx4 oacc[2][4];
#pragma unroll
    for (int rt = 0; rt < 2; rt++)
#pragma unroll
        for (int dt = 0; dt < 4; dt++) oacc[rt][dt] = (floatx4){0.f, 0.f, 0.f, 0.f};
    float lsum[2] = {0.f, 0.f};

    for (int kt = 0; kt < 16; ++kt) {
        __syncthreads();
        // stage K tile (keys kt*64..+64): wave w handles key sub-tile kt4=w
#pragma unroll
        for (int ks = 0; ks < 2; ks++) {
            int token = m + 4 * (kt * 64 + w * 16 + c);
            async_copy16(Kg + (rowBase + token) * 1024 + h * 64 + ks * 32 + g * 8,
                         Ks + (w * 2 + ks) * 512);
        }
        // stage V^T tile: wave w handles d sub-tile dt=w
#pragma unroll
        for (int kc = 0; kc < 2; kc++) {
            async_copy16(VtS + (size_t)(w * 16 + c) * 1024 + kt * 64 + kc * 32 + g * 8,
                         Vs + (w * 2 + kc) * 512);
        }
        __syncthreads();

        // S^T[key][q] = K·Q^T : A=K (4 key-tiles), B=Q (2 q-tiles)
        floatx4 sacc[4][2];
#pragma unroll
        for (int k4 = 0; k4 < 4; k4++)
#pragma unroll
            for (int rt = 0; rt < 2; rt++) sacc[k4][rt] = (floatx4){0.f, 0.f, 0.f, 0.f};
#pragma unroll
        for (int ks = 0; ks < 2; ks++) {
            short8 kf[4], qf[2];
#pragma unroll
            for (int k4 = 0; k4 < 4; k4++)
                kf[k4] = *(const short8*)(Ks + (((k4 * 2 + ks) * 4 + g) * 16 + c) * 8);
#pragma unroll
            for (int rt = 0; rt < 2; rt++)
                qf[rt] = *(const short8*)(Qs + ((((w * 2 + rt) * 2 + ks) * 4 + g) * 16 + c) * 8);
#pragma unroll
            for (int k4 = 0; k4 < 4; k4++)
#pragma unroll
                for (int rt = 0; rt < 2; rt++)
                    sacc[k4][rt] = __builtin_amdgcn_mfma_f32_16x16x32_bf16(kf[k4], qf[rt], sacc[k4][rt], 0, 0, 0);
        }

        // p = exp2(s) (no max-sub), accumulate l partials, pack -> Ps (per-wave)
#pragma unroll
        for (int k4 = 0; k4 < 4; k4++) {
            const int kc = k4 >> 1;
            const int gr = (k4 & 1) * 2 + (g >> 1);
            const int j0 = (g & 1) * 4;
#pragma unroll
            for (int rt = 0; rt < 2; rt++) {
                float e0 = __builtin_amdgcn_exp2f(sacc[k4][rt][0]);
                float e1 = __builtin_amdgcn_exp2f(sacc[k4][rt][1]);
                float e2 = __builtin_amdgcn_exp2f(sacc[k4][rt][2]);
                float e3 = __builtin_amdgcn_exp2f(sacc[k4][rt][3]);
                lsum[rt] += (e0 + e1) + (e2 + e3);
                uint2 pk;
                pk.x = pack2bf(e0, e1);
                pk.y = pack2bf(e2, e3);
                *(uint2*)(Ps + w * 2048 + (((rt * 2 + kc) * 4 + gr) * 16 + c) * 8 + j0) = pk;
            }
        }

        // O += P·V : A=P (2 q-tiles), B=V^T (4 d-tiles), K=64 keys (2 chunks)
#pragma unroll
        for (int kc = 0; kc < 2; kc++) {
            short8 pf[2], vf[4];
#pragma unroll
            for (int rt = 0; rt < 2; rt++)
                pf[rt] = *(const short8*)(Ps + w * 2048 + (((rt * 2 + kc) * 4 + g) * 16 + c) * 8);
#pragma unroll
            for (int dt = 0; dt < 4; dt++)
                vf[dt] = *(const short8*)(Vs + (((dt * 2 + kc) * 4 + g) * 16 + c) * 8);
#pragma unroll
            for (int rt = 0; rt < 2; rt++)
#pragma unroll
                for (int dt = 0; dt < 4; dt++)
                    oacc[rt][dt] = __builtin_amdgcn_mfma_f32_16x16x32_bf16(pf[rt], vf[dt], oacc[rt][dt], 0, 0, 0);
        }
    }

    // final l reduce across g-groups (lanes differing by 16/32), broadcast 1/l via LDS
#pragma unroll
    for (int rt = 0; rt < 2; rt++) {
        float l = lsum[rt];
        l += __shfl_xor(l, 16, 64);
        l += __shfl_xor(l, 32, 64);
        if (lane < 16) als[w * 32 + rt * 16 + c] = 1.0f / l;
    }
    float4 li[2];
#pragma unroll
    for (int rt = 0; rt < 2; rt++) li[rt] = *(float4*)(&als[w * 32 + rt * 16 + g * 4]);

#pragma unroll
    for (int rt = 0; rt < 2; rt++) {
#pragma unroll
        for (int r = 0; r < 4; r++) {
            float inv = (r == 0) ? li[rt].x : (r == 1) ? li[rt].y : (r == 2) ? li[rt].z : li[rt].w;
            int token = m + 4 * (qt * 128 + w * 32 + rt * 16 + g * 4 + r);
            size_t rowOff = (rowBase + token) * 1024 + h * 64;
#pragma unroll
            for (int dt = 0; dt < 4; dt++)
                Og[rowOff + dt * 16 + c] = f2b(oacc[rt][dt][r] * inv);
        }
    }
}

extern "C" void kernel_launch(void* const* d_in, const int* in_sizes, int n_in,
                              void* d_out, int out_size, void* d_ws, size_t ws_size,
                              hipStream_t stream) {
    const float* x  = (const float*)d_in[0];
    const float* Wq = (const float*)d_in[1];
    const float* bq = (const float*)d_in[2];
    const float* Wk = (const float*)d_in[3];
    const float* bk = (const float*)d_in[4];
    const float* Wv = (const float*)d_in[5];
    const float* bv = (const float*)d_in[6];
    const float* Wo = (const float*)d_in[7];
    const float* bo = (const float*)d_in[8];

    const float SC = 0.18033688011112042f;  // (1/8) * log2(e), folded into Wq/bq

    char* ws = (char*)d_ws;
    const size_t SZ = 33554432;  // 32 MB = 16M bf16
    unsigned short* xb  = (unsigned short*)(ws);          // dead after QKV gemm
    unsigned short* Vtp = (unsigned short*)(ws);          // reuses xb region
    unsigned short* qb  = (unsigned short*)(ws + SZ);     // q,k,v contiguous
    unsigned short* ob  = (unsigned short*)(ws + 4 * SZ);
    unsigned short* Wt3 = (unsigned short*)(ws + 5 * SZ);
    unsigned short* Wot = Wt3 + 3ull * 1024 * 1024;

    cvt_kernel<<<16384, 256, 0, stream>>>(x, xb, 4194304);
    cvt_w_t<<<dim3(16, 16), 256, 0, stream>>>(Wq, Wt3, SC);
    cvt_w_t<<<dim3(16, 16), 256, 0, stream>>>(Wk, Wt3 + 1048576, 1.0f);
    cvt_w_t<<<dim3(16, 16), 256, 0, stream>>>(Wv, Wt3 + 2097152, 1.0f);
    cvt_w_t<<<dim3(16, 16), 256, 0, stream>>>(Wo, Wot, 1.0f);
    gemm_k<false><<<dim3(8, 128, 3), 256, 0, stream>>>(xb, Wt3, bq, bk, bv, qb, SC);
    vtrans<<<dim3(16, 256), 256, 0, stream>>>(qb + 2ull * 16777216ull, Vtp);
    attn_k<<<dim3(8, 256), 256, 0, stream>>>(qb, qb + 16777216ull, Vtp, ob);
    gemm_k<true><<<dim3(8, 128, 1), 256, 0, stream>>>(ob, Wot, bo, bo, bo, d_out, 1.0f);
}

// Round 5
// 433.417 us; speedup vs baseline: 1.2381x; 1.0711x over previous
//
#include <hip/hip_runtime.h>
#include <hip/hip_bf16.h>

// B=4, L=4096, D=1024, H=16, M=4, dk=64, n=1024. All-bf16 MFMA pipeline.
// R5: XCD-aware 1-D grid swizzle. gemm: xcd=id&7 owns tileM stripe [16*xcd,+16),
// iterates tileM fastest within each (tileN,z) -> A stays L2-resident per XCD
// (4MB), B-tile fetched once per rz and reused 16x. R4 FETCH was 399MB vs 38MB
// ideal because the 8 blocks sharing an A-tile scattered across all 8 XCDs.
// attn: xcd owns 32 slices, qt fastest -> K/V (256KB/slice) L2-resident.

typedef __attribute__((ext_vector_type(8))) short short8;
typedef __attribute__((ext_vector_type(8))) unsigned short ushort8v;
typedef __attribute__((ext_vector_type(4))) float floatx4;

__device__ __forceinline__ float b2f(unsigned short h) {
    union { unsigned int u; float f; } v; v.u = ((unsigned int)h) << 16; return v.f;
}
__device__ __forceinline__ unsigned short f2b(float f) {
    union { float f; unsigned int u; } v; v.f = f;
    unsigned int r = v.u + 0x7fffu + ((v.u >> 16) & 1u);
    return (unsigned short)(r >> 16);
}
// pack two non-negative floats to bf16 pair (round-half-up; inputs are exp2 outputs >= 0)
__device__ __forceinline__ unsigned int pack2bf(float lo, float hi) {
    union { float f; unsigned int u; } a, b; a.f = lo; b.f = hi;
    return ((b.u + 0x8000u) & 0xFFFF0000u) | (((a.u + 0x8000u) >> 16) & 0xFFFFu);
}
__device__ __forceinline__ void async_copy16(const unsigned short* g, unsigned short* l) {
    __builtin_amdgcn_global_load_lds((const __attribute__((address_space(1))) void*)g,
                                     (__attribute__((address_space(3))) void*)l, 16, 0, 0);
}

// ---------------- fp32 -> bf16 convert (x) ----------------
__global__ __launch_bounds__(256)
void cvt_kernel(const float* __restrict__ in, unsigned short* __restrict__ out, int n4) {
    int i = blockIdx.x * 256 + threadIdx.x;
    if (i >= n4) return;
    float4 v = ((const float4*)in)[i];
    ushort4 o;
    o.x = f2b(v.x); o.y = f2b(v.y); o.z = f2b(v.z); o.w = f2b(v.w);
    ((ushort4*)out)[i] = o;
}

// ---------------- W [K][N] fp32 -> Wt [N][K] bf16 (optionally scaled) ----------------
__global__ __launch_bounds__(256)
void cvt_w_t(const float* __restrict__ W, unsigned short* __restrict__ Wt, float sc) {
    __shared__ float tile[64][65];
    const int kt = blockIdx.x, nt = blockIdx.y;
    const int t = threadIdx.x;
    const int r = t >> 2, cg = t & 3;
    const float* src = W + (size_t)(kt * 64 + r) * 1024 + nt * 64 + cg * 16;
#pragma unroll
    for (int j = 0; j < 4; j++) {
        float4 v = *(const float4*)(src + j * 4);
        tile[r][cg * 16 + j * 4 + 0] = v.x;
        tile[r][cg * 16 + j * 4 + 1] = v.y;
        tile[r][cg * 16 + j * 4 + 2] = v.z;
        tile[r][cg * 16 + j * 4 + 3] = v.w;
    }
    __syncthreads();
    unsigned short* dst = Wt + (size_t)(nt * 64 + r) * 1024 + kt * 64 + cg * 16;
    ushort8v o0, o1;
#pragma unroll
    for (int j = 0; j < 8; j++) o0[j] = f2b(tile[cg * 16 + j][r] * sc);
#pragma unroll
    for (int j = 0; j < 8; j++) o1[j] = f2b(tile[cg * 16 + 8 + j][r] * sc);
    *(ushort8v*)(dst) = o0;
    *(ushort8v*)(dst + 8) = o1;
}

// ---------------- GEMM: C[M][N] = A[M][K] * Bt[N][K]^T + bias*bs ----------------
// 128x128 tile, BK=64, 4 waves (2x2), 4x4 16x16x32 MFMA per wave.
// LDS: chunk(row,kc) @ elem (row*8 + (kc^(row&7)))*8 (XOR swizzle, R4).
// Grid: 1-D 1024*nz blocks; decode xcd=id&7, q=id>>3, tileM=xcd*16+(q&15),
// rz=q>>4, tileN=rz&7, z=rz>>3.
template <bool F32OUT>
__global__ __launch_bounds__(256)
void gemm_k(const unsigned short* __restrict__ A,
            const unsigned short* __restrict__ BtBase,
            const float* __restrict__ bias0,
            const float* __restrict__ bias1,
            const float* __restrict__ bias2,
            void* __restrict__ OutBase, float s0) {
    constexpr int K = 1024, N = 1024;
    __shared__ __align__(16) unsigned short As[128 * 64];
    __shared__ __align__(16) unsigned short Bs[128 * 64];
    const int id = blockIdx.x;
    const int xcd = id & 7;
    const int q = id >> 3;
    const int tileM = xcd * 16 + (q & 15);
    const int rz = q >> 4;
    const int tileN = rz & 7;
    const int z = rz >> 3;
    const unsigned short* Bt = BtBase + (size_t)z * (1024 * 1024);
    const float* bias = (z == 0) ? bias0 : (z == 1 ? bias1 : bias2);
    const float bs = (z == 0) ? s0 : 1.0f;
    const int tid = threadIdx.x, w = tid >> 6, lane = tid & 63;
    const int wr = w >> 1, wc = w & 1;
    const int g = lane >> 4, c = lane & 15;
    const int c7 = c & 7;
    const int r8 = lane >> 3, j8 = lane & 7;
    const int kcs = (j8 ^ r8) * 8;   // swizzled k-chunk this lane stages

    floatx4 acc[4][4];
#pragma unroll
    for (int i = 0; i < 4; i++)
#pragma unroll
        for (int jj = 0; jj < 4; jj++) acc[i][jj] = (floatx4){0.f, 0.f, 0.f, 0.f};

    for (int kt = 0; kt < K / 64; ++kt) {
        __syncthreads();
#pragma unroll
        for (int t = 0; t < 4; t++) {
            int seg = w * 4 + t;                 // 0..15, covers rows seg*8..+7
            int rowA = tileM * 128 + seg * 8 + r8;
            async_copy16(A + (size_t)rowA * K + kt * 64 + kcs, As + seg * 512);
            int rowB = tileN * 128 + seg * 8 + r8;
            async_copy16(Bt + (size_t)rowB * K + kt * 64 + kcs, Bs + seg * 512);
        }
        __syncthreads();
#pragma unroll
        for (int ks = 0; ks < 2; ks++) {
            short8 af[4], bf[4];
            const int kx = ((ks * 4 + g) ^ c7) * 8;  // swizzled chunk offset for read
#pragma unroll
            for (int rt = 0; rt < 4; rt++)
                af[rt] = *(const short8*)(As + (wr * 64 + rt * 16 + c) * 64 + kx);
#pragma unroll
            for (int ct = 0; ct < 4; ct++)
                bf[ct] = *(const short8*)(Bs + (wc * 64 + ct * 16 + c) * 64 + kx);
#pragma unroll
            for (int rt = 0; rt < 4; rt++)
#pragma unroll
                for (int ct = 0; ct < 4; ct++)
                    acc[rt][ct] = __builtin_amdgcn_mfma_f32_16x16x32_bf16(af[rt], bf[ct], acc[rt][ct], 0, 0, 0);
        }
    }
#pragma unroll
    for (int ct = 0; ct < 4; ct++) {
        int col = tileN * 128 + wc * 64 + ct * 16 + c;
        float bvv = bias[col] * bs;
#pragma unroll
        for (int rt = 0; rt < 4; rt++) {
            int row0 = tileM * 128 + wr * 64 + rt * 16 + g * 4;
#pragma unroll
            for (int r = 0; r < 4; r++) {
                float v = acc[rt][ct][r] + bvv;
                if (F32OUT) {
                    ((float*)OutBase)[(size_t)(row0 + r) * N + col] = v;
                } else {
                    ((unsigned short*)OutBase)[(size_t)z * (16384ull * 1024ull) +
                                               (size_t)(row0 + r) * N + col] = f2b(v);
                }
            }
        }
    }
}

// ---------------- V transpose: v[B,L,D] -> Vt[slice=(b,h,m)][d=64][i=1024] ----------------
__global__ __launch_bounds__(256)
void vtrans(const unsigned short* __restrict__ V, unsigned short* __restrict__ Vt) {
    __shared__ unsigned short tile[64 * 72];
    const int it = blockIdx.x, s = blockIdx.y;
    const int m = s & 3, h = (s >> 2) & 15, b = s >> 6;
    const int tid = threadIdx.x;
    {
        int il = tid >> 2, cg = tid & 3;
        const unsigned short* gsrc =
            V + ((size_t)b * 4096 + m + 4 * (it * 64 + il)) * 1024 + h * 64 + cg * 16;
        *(ushort8v*)(tile + il * 72 + cg * 16) = *(const ushort8v*)gsrc;
        *(ushort8v*)(tile + il * 72 + cg * 16 + 8) = *(const ushort8v*)(gsrc + 8);
    }
    __syncthreads();
    {
        int dl = tid >> 2, ig = (tid & 3) * 16;
        ushort8v o0, o1;
#pragma unroll
        for (int j = 0; j < 8; j++) o0[j] = tile[(ig + j) * 72 + dl];
#pragma unroll
        for (int j = 0; j < 8; j++) o1[j] = tile[(ig + 8 + j) * 72 + dl];
        unsigned short* dst = Vt + (size_t)s * 65536 + (size_t)dl * 1024 + it * 64 + ig;
        *(ushort8v*)dst = o0;
        *(ushort8v*)(dst + 8) = o1;
    }
}

// ---------------- Attention ----------------
// 1-D grid 2048 blocks; decode xcd=id&7, q=id>>3, s=xcd*32+(q>>3), qt=q&7 ->
// the 8 q-tile blocks of a slice run on one XCD (K/V L2-resident).
// S^T = K·Q^T (both natural), softmax without max-sub (scale folded into Wq
// as 0.125*log2e), P packed b64 into per-wave LDS, O = P·V (V^T staged).
__global__ __launch_bounds__(256)
void attn_k(const unsigned short* __restrict__ Qg,
            const unsigned short* __restrict__ Kg,
            const unsigned short* __restrict__ Vt,
            unsigned short* __restrict__ Og) {
    __shared__ __align__(16) unsigned short Qs[128 * 64];   // [w][rt][ks][g][c][8]
    __shared__ __align__(16) unsigned short Ks[64 * 64];    // [kt4][ks][g][c][8]
    __shared__ __align__(16) unsigned short Vs[64 * 64];    // [dt][kc][g][c][8]
    __shared__ __align__(16) unsigned short Ps[4 * 2048];   // per-wave [rt*2+kc][g][c][8]
    __shared__ float als[128];

    const int id = blockIdx.x;
    const int xcd = id & 7;
    const int qq = id >> 3;
    const int s = xcd * 32 + (qq >> 3);
    const int qt = qq & 7;
    const int m = s & 3, h = (s >> 2) & 15, b = s >> 6;
    const int tid = threadIdx.x, w = tid >> 6, lane = tid & 63;
    const int g = lane >> 4, c = lane & 15;
    const size_t rowBase = (size_t)b * 4096;
    const unsigned short* VtS = Vt + (size_t)s * 65536;

    // stage Q (already scaled via Wq fold): 4 async copies per wave
#pragma unroll
    for (int rt = 0; rt < 2; rt++)
#pragma unroll
        for (int ks = 0; ks < 2; ks++) {
            int token = m + 4 * (qt * 128 + w * 32 + rt * 16 + c);
            async_copy16(Qg + (rowBase + token) * 1024 + h * 64 + ks * 32 + g * 8,
                         Qs + ((w * 2 + rt) * 2 + ks) * 512);
        }

    floatx4 oacc[2][4];
#pragma unroll
    for (int rt = 0; rt < 2; rt++)
#pragma unroll
        for (int dt = 0; dt < 4; dt++) oacc[rt][dt] = (floatx4){0.f, 0.f, 0.f, 0.f};
    float lsum[2] = {0.f, 0.f};

    for (int kt = 0; kt < 16; ++kt) {
        __syncthreads();
        // stage K tile (keys kt*64..+64): wave w handles key sub-tile kt4=w
#pragma unroll
        for (int ks = 0; ks < 2; ks++) {
            int token = m + 4 * (kt * 64 + w * 16 + c);
            async_copy16(Kg + (rowBase + token) * 1024 + h * 64 + ks * 32 + g * 8,
                         Ks + (w * 2 + ks) * 512);
        }
        // stage V^T tile: wave w handles d sub-tile dt=w
#pragma unroll
        for (int kc = 0; kc < 2; kc++) {
            async_copy16(VtS + (size_t)(w * 16 + c) * 1024 + kt * 64 + kc * 32 + g * 8,
                         Vs + (w * 2 + kc) * 512);
        }
        __syncthreads();

        // S^T[key][q] = K·Q^T : A=K (4 key-tiles), B=Q (2 q-tiles)
        floatx4 sacc[4][2];
#pragma unroll
        for (int k4 = 0; k4 < 4; k4++)
#pragma unroll
            for (int rt = 0; rt < 2; rt++) sacc[k4][rt] = (floatx4){0.f, 0.f, 0.f, 0.f};
#pragma unroll
        for (int ks = 0; ks < 2; ks++) {
            short8 kf[4], qf[2];
#pragma unroll
            for (int k4 = 0; k4 < 4; k4++)
                kf[k4] = *(const short8*)(Ks + (((k4 * 2 + ks) * 4 + g) * 16 + c) * 8);
#pragma unroll
            for (int rt = 0; rt < 2; rt++)
                qf[rt] = *(const short8*)(Qs + ((((w * 2 + rt) * 2 + ks) * 4 + g) * 16 + c) * 8);
#pragma unroll
            for (int k4 = 0; k4 < 4; k4++)
#pragma unroll
                for (int rt = 0; rt < 2; rt++)
                    sacc[k4][rt] = __builtin_amdgcn_mfma_f32_16x16x32_bf16(kf[k4], qf[rt], sacc[k4][rt], 0, 0, 0);
        }

        // p = exp2(s) (no max-sub), accumulate l partials, pack -> Ps (per-wave)
#pragma unroll
        for (int k4 = 0; k4 < 4; k4++) {
            const int kc = k4 >> 1;
            const int gr = (k4 & 1) * 2 + (g >> 1);
            const int j0 = (g & 1) * 4;
#pragma unroll
            for (int rt = 0; rt < 2; rt++) {
                float e0 = __builtin_amdgcn_exp2f(sacc[k4][rt][0]);
                float e1 = __builtin_amdgcn_exp2f(sacc[k4][rt][1]);
                float e2 = __builtin_amdgcn_exp2f(sacc[k4][rt][2]);
                float e3 = __builtin_amdgcn_exp2f(sacc[k4][rt][3]);
                lsum[rt] += (e0 + e1) + (e2 + e3);
                uint2 pk;
                pk.x = pack2bf(e0, e1);
                pk.y = pack2bf(e2, e3);
                *(uint2*)(Ps + w * 2048 + (((rt * 2 + kc) * 4 + gr) * 16 + c) * 8 + j0) = pk;
            }
        }

        // O += P·V : A=P (2 q-tiles), B=V^T (4 d-tiles), K=64 keys (2 chunks)
#pragma unroll
        for (int kc = 0; kc < 2; kc++) {
            short8 pf[2], vf[4];
#pragma unroll
            for (int rt = 0; rt < 2; rt++)
                pf[rt] = *(const short8*)(Ps + w * 2048 + (((rt * 2 + kc) * 4 + g) * 16 + c) * 8);
#pragma unroll
            for (int dt = 0; dt < 4; dt++)
                vf[dt] = *(const short8*)(Vs + (((dt * 2 + kc) * 4 + g) * 16 + c) * 8);
#pragma unroll
            for (int rt = 0; rt < 2; rt++)
#pragma unroll
                for (int dt = 0; dt < 4; dt++)
                    oacc[rt][dt] = __builtin_amdgcn_mfma_f32_16x16x32_bf16(pf[rt], vf[dt], oacc[rt][dt], 0, 0, 0);
        }
    }

    // final l reduce across g-groups (lanes differing by 16/32), broadcast 1/l via LDS
#pragma unroll
    for (int rt = 0; rt < 2; rt++) {
        float l = lsum[rt];
        l += __shfl_xor(l, 16, 64);
        l += __shfl_xor(l, 32, 64);
        if (lane < 16) als[w * 32 + rt * 16 + c] = 1.0f / l;
    }
    float4 li[2];
#pragma unroll
    for (int rt = 0; rt < 2; rt++) li[rt] = *(float4*)(&als[w * 32 + rt * 16 + g * 4]);

#pragma unroll
    for (int rt = 0; rt < 2; rt++) {
#pragma unroll
        for (int r = 0; r < 4; r++) {
            float inv = (r == 0) ? li[rt].x : (r == 1) ? li[rt].y : (r == 2) ? li[rt].z : li[rt].w;
            int token = m + 4 * (qt * 128 + w * 32 + rt * 16 + g * 4 + r);
            size_t rowOff = (rowBase + token) * 1024 + h * 64;
#pragma unroll
            for (int dt = 0; dt < 4; dt++)
                Og[rowOff + dt * 16 + c] = f2b(oacc[rt][dt][r] * inv);
        }
    }
}

extern "C" void kernel_launch(void* const* d_in, const int* in_sizes, int n_in,
                              void* d_out, int out_size, void* d_ws, size_t ws_size,
                              hipStream_t stream) {
    const float* x  = (const float*)d_in[0];
    const float* Wq = (const float*)d_in[1];
    const float* bq = (const float*)d_in[2];
    const float* Wk = (const float*)d_in[3];
    const float* bk = (const float*)d_in[4];
    const float* Wv = (const float*)d_in[5];
    const float* bv = (const float*)d_in[6];
    const float* Wo = (const float*)d_in[7];
    const float* bo = (const float*)d_in[8];

    const float SC = 0.18033688011112042f;  // (1/8) * log2(e), folded into Wq/bq

    char* ws = (char*)d_ws;
    const size_t SZ = 33554432;  // 32 MB = 16M bf16
    unsigned short* xb  = (unsigned short*)(ws);          // dead after QKV gemm
    unsigned short* Vtp = (unsigned short*)(ws);          // reuses xb region
    unsigned short* qb  = (unsigned short*)(ws + SZ);     // q,k,v contiguous
    unsigned short* ob  = (unsigned short*)(ws + 4 * SZ);
    unsigned short* Wt3 = (unsigned short*)(ws + 5 * SZ);
    unsigned short* Wot = Wt3 + 3ull * 1024 * 1024;

    cvt_kernel<<<16384, 256, 0, stream>>>(x, xb, 4194304);
    cvt_w_t<<<dim3(16, 16), 256, 0, stream>>>(Wq, Wt3, SC);
    cvt_w_t<<<dim3(16, 16), 256, 0, stream>>>(Wk, Wt3 + 1048576, 1.0f);
    cvt_w_t<<<dim3(16, 16), 256, 0, stream>>>(Wv, Wt3 + 2097152, 1.0f);
    cvt_w_t<<<dim3(16, 16), 256, 0, stream>>>(Wo, Wot, 1.0f);
    gemm_k<false><<<3072, 256, 0, stream>>>(xb, Wt3, bq, bk, bv, qb, SC);
    vtrans<<<dim3(16, 256), 256, 0, stream>>>(qb + 2ull * 16777216ull, Vtp);
    attn_k<<<2048, 256, 0, stream>>>(qb, qb + 16777216ull, Vtp, ob);
    gemm_k<true><<<1024, 256, 0, stream>>>(ob, Wot, bo, bo, bo, d_out, 1.0f);
}

// Round 6
// 411.773 us; speedup vs baseline: 1.3032x; 1.0526x over previous
//
#include <hip/hip_runtime.h>
#include <hip/hip_bf16.h>

// B=4, L=4096, D=1024, H=16, M=4, dk=64, n=1024. All-bf16 MFMA pipeline.
// R6: gemm tile 128x128 -> 256x128 (BM=256). Doubles MFMA per barrier round
// (64/wave-iter), staging only 1.5x -> barrier drain amortized 2x, L2 intensity
// 85 FLOP/B. 1536 blocks = 6/CU stays oversubscribed (unlike m105's 256-block
// starve). XOR-swizzled LDS (R4) + XCD-stripe decode (R5) kept. cvt_w merged.

typedef __attribute__((ext_vector_type(8))) short short8;
typedef __attribute__((ext_vector_type(8))) unsigned short ushort8v;
typedef __attribute__((ext_vector_type(4))) float floatx4;

__device__ __forceinline__ float b2f(unsigned short h) {
    union { unsigned int u; float f; } v; v.u = ((unsigned int)h) << 16; return v.f;
}
__device__ __forceinline__ unsigned short f2b(float f) {
    union { float f; unsigned int u; } v; v.f = f;
    unsigned int r = v.u + 0x7fffu + ((v.u >> 16) & 1u);
    return (unsigned short)(r >> 16);
}
__device__ __forceinline__ unsigned int pack2bf(float lo, float hi) {
    union { float f; unsigned int u; } a, b; a.f = lo; b.f = hi;
    return ((b.u + 0x8000u) & 0xFFFF0000u) | (((a.u + 0x8000u) >> 16) & 0xFFFFu);
}
__device__ __forceinline__ void async_copy16(const unsigned short* g, unsigned short* l) {
    __builtin_amdgcn_global_load_lds((const __attribute__((address_space(1))) void*)g,
                                     (__attribute__((address_space(3))) void*)l, 16, 0, 0);
}

// ---------------- fp32 -> bf16 convert (x) ----------------
__global__ __launch_bounds__(256)
void cvt_kernel(const float* __restrict__ in, unsigned short* __restrict__ out, int n4) {
    int i = blockIdx.x * 256 + threadIdx.x;
    if (i >= n4) return;
    float4 v = ((const float4*)in)[i];
    ushort4 o;
    o.x = f2b(v.x); o.y = f2b(v.y); o.z = f2b(v.z); o.w = f2b(v.w);
    ((ushort4*)out)[i] = o;
}

// ---------------- W [K][N] fp32 -> Wt [N][K] bf16, all 4 weights in one grid ----------------
__global__ __launch_bounds__(256)
void cvt_w_t(const float* __restrict__ Wq, const float* __restrict__ Wk,
             const float* __restrict__ Wv, const float* __restrict__ Wo,
             unsigned short* __restrict__ Wt3, unsigned short* __restrict__ Wot, float s0) {
    __shared__ float tile[64][65];
    const int kt = blockIdx.x, nt = blockIdx.y, z = blockIdx.z;
    const float* W = (z == 0) ? Wq : (z == 1) ? Wk : (z == 2) ? Wv : Wo;
    unsigned short* Wt = (z < 3) ? (Wt3 + (size_t)z * 1048576) : Wot;
    const float sc = (z == 0) ? s0 : 1.0f;
    const int t = threadIdx.x;
    const int r = t >> 2, cg = t & 3;
    const float* src = W + (size_t)(kt * 64 + r) * 1024 + nt * 64 + cg * 16;
#pragma unroll
    for (int j = 0; j < 4; j++) {
        float4 v = *(const float4*)(src + j * 4);
        tile[r][cg * 16 + j * 4 + 0] = v.x;
        tile[r][cg * 16 + j * 4 + 1] = v.y;
        tile[r][cg * 16 + j * 4 + 2] = v.z;
        tile[r][cg * 16 + j * 4 + 3] = v.w;
    }
    __syncthreads();
    unsigned short* dst = Wt + (size_t)(nt * 64 + r) * 1024 + kt * 64 + cg * 16;
    ushort8v o0, o1;
#pragma unroll
    for (int j = 0; j < 8; j++) o0[j] = f2b(tile[cg * 16 + j][r] * sc);
#pragma unroll
    for (int j = 0; j < 8; j++) o1[j] = f2b(tile[cg * 16 + 8 + j][r] * sc);
    *(ushort8v*)(dst) = o0;
    *(ushort8v*)(dst + 8) = o1;
}

// ---------------- GEMM: C[M][N] = A[M][K] * Bt[N][K]^T + bias*bs ----------------
// BM=256, BN=128, BK=64; 4 waves (2x2): wave rows wr*128+rt*16 (rt 0..7),
// cols wc*64+ct*16. 8x4 accum/wave = 64 MFMA per K-iter per wave.
// LDS XOR swizzle: chunk(row,kc) @ elem (row*8 + (kc^(row&7)))*8.
// Grid 512*nz: xcd=id&7, q=id>>3, tileM=xcd*8+(q&7), rz=q>>3, tileN=rz&7, z=rz>>3.
template <bool F32OUT>
__global__ __launch_bounds__(256, 2)
void gemm_k(const unsigned short* __restrict__ A,
            const unsigned short* __restrict__ BtBase,
            const float* __restrict__ bias0,
            const float* __restrict__ bias1,
            const float* __restrict__ bias2,
            void* __restrict__ OutBase, float s0) {
    constexpr int K = 1024, N = 1024;
    __shared__ __align__(16) unsigned short As[256 * 64];
    __shared__ __align__(16) unsigned short Bs[128 * 64];
    const int id = blockIdx.x;
    const int xcd = id & 7;
    const int q = id >> 3;
    const int tileM = xcd * 8 + (q & 7);
    const int rz = q >> 3;
    const int tileN = rz & 7;
    const int z = rz >> 3;
    const unsigned short* Bt = BtBase + (size_t)z * (1024 * 1024);
    const float* bias = (z == 0) ? bias0 : (z == 1 ? bias1 : bias2);
    const float bs = (z == 0) ? s0 : 1.0f;
    const int tid = threadIdx.x, w = tid >> 6, lane = tid & 63;
    const int wr = w >> 1, wc = w & 1;
    const int g = lane >> 4, c = lane & 15;
    const int c7 = c & 7;
    const int r8 = lane >> 3, j8 = lane & 7;
    const int kcs = (j8 ^ r8) * 8;   // swizzled k-chunk this lane stages

    floatx4 acc[8][4];
#pragma unroll
    for (int i = 0; i < 8; i++)
#pragma unroll
        for (int jj = 0; jj < 4; jj++) acc[i][jj] = (floatx4){0.f, 0.f, 0.f, 0.f};

    for (int kt = 0; kt < K / 64; ++kt) {
        __syncthreads();
#pragma unroll
        for (int t = 0; t < 8; t++) {          // A: 32 segs of 8 rows
            int seg = w * 8 + t;
            int rowA = tileM * 256 + seg * 8 + r8;
            async_copy16(A + (size_t)rowA * K + kt * 64 + kcs, As + seg * 512);
        }
#pragma unroll
        for (int t = 0; t < 4; t++) {          // B: 16 segs of 8 rows
            int seg = w * 4 + t;
            int rowB = tileN * 128 + seg * 8 + r8;
            async_copy16(Bt + (size_t)rowB * K + kt * 64 + kcs, Bs + seg * 512);
        }
        __syncthreads();
#pragma unroll
        for (int ks = 0; ks < 2; ks++) {
            const int kx = ((ks * 4 + g) ^ c7) * 8;
            short8 bf[4];
#pragma unroll
            for (int ct = 0; ct < 4; ct++)
                bf[ct] = *(const short8*)(Bs + (wc * 64 + ct * 16 + c) * 64 + kx);
#pragma unroll
            for (int rt = 0; rt < 8; rt++) {
                short8 af = *(const short8*)(As + (wr * 128 + rt * 16 + c) * 64 + kx);
#pragma unroll
                for (int ct = 0; ct < 4; ct++)
                    acc[rt][ct] = __builtin_amdgcn_mfma_f32_16x16x32_bf16(af, bf[ct], acc[rt][ct], 0, 0, 0);
            }
        }
    }
#pragma unroll
    for (int ct = 0; ct < 4; ct++) {
        int col = tileN * 128 + wc * 64 + ct * 16 + c;
        float bvv = bias[col] * bs;
#pragma unroll
        for (int rt = 0; rt < 8; rt++) {
            int row0 = tileM * 256 + wr * 128 + rt * 16 + g * 4;
#pragma unroll
            for (int r = 0; r < 4; r++) {
                float v = acc[rt][ct][r] + bvv;
                if (F32OUT) {
                    ((float*)OutBase)[(size_t)(row0 + r) * N + col] = v;
                } else {
                    ((unsigned short*)OutBase)[(size_t)z * (16384ull * 1024ull) +
                                               (size_t)(row0 + r) * N + col] = f2b(v);
                }
            }
        }
    }
}

// ---------------- V transpose: v[B,L,D] -> Vt[slice=(b,h,m)][d=64][i=1024] ----------------
__global__ __launch_bounds__(256)
void vtrans(const unsigned short* __restrict__ V, unsigned short* __restrict__ Vt) {
    __shared__ unsigned short tile[64 * 72];
    const int it = blockIdx.x, s = blockIdx.y;
    const int m = s & 3, h = (s >> 2) & 15, b = s >> 6;
    const int tid = threadIdx.x;
    {
        int il = tid >> 2, cg = tid & 3;
        const unsigned short* gsrc =
            V + ((size_t)b * 4096 + m + 4 * (it * 64 + il)) * 1024 + h * 64 + cg * 16;
        *(ushort8v*)(tile + il * 72 + cg * 16) = *(const ushort8v*)gsrc;
        *(ushort8v*)(tile + il * 72 + cg * 16 + 8) = *(const ushort8v*)(gsrc + 8);
    }
    __syncthreads();
    {
        int dl = tid >> 2, ig = (tid & 3) * 16;
        ushort8v o0, o1;
#pragma unroll
        for (int j = 0; j < 8; j++) o0[j] = tile[(ig + j) * 72 + dl];
#pragma unroll
        for (int j = 0; j < 8; j++) o1[j] = tile[(ig + 8 + j) * 72 + dl];
        unsigned short* dst = Vt + (size_t)s * 65536 + (size_t)dl * 1024 + it * 64 + ig;
        *(ushort8v*)dst = o0;
        *(ushort8v*)(dst + 8) = o1;
    }
}

// ---------------- Attention ----------------
// 1-D grid 2048 blocks; decode xcd=id&7, q=id>>3, s=xcd*32+(q>>3), qt=q&7.
// S^T = K·Q^T (both natural), softmax without max-sub (scale folded into Wq),
// P packed b64 into per-wave LDS, O = P·V (V^T staged).
__global__ __launch_bounds__(256)
void attn_k(const unsigned short* __restrict__ Qg,
            const unsigned short* __restrict__ Kg,
            const unsigned short* __restrict__ Vt,
            unsigned short* __restrict__ Og) {
    __shared__ __align__(16) unsigned short Qs[128 * 64];   // [w][rt][ks][g][c][8]
    __shared__ __align__(16) unsigned short Ks[64 * 64];    // [kt4][ks][g][c][8]
    __shared__ __align__(16) unsigned short Vs[64 * 64];    // [dt][kc][g][c][8]
    __shared__ __align__(16) unsigned short Ps[4 * 2048];   // per-wave [rt*2+kc][g][c][8]
    __shared__ float als[128];

    const int id = blockIdx.x;
    const int xcd = id & 7;
    const int qq = id >> 3;
    const int s = xcd * 32 + (qq >> 3);
    const int qt = qq & 7;
    const int m = s & 3, h = (s >> 2) & 15, b = s >> 6;
    const int tid = threadIdx.x, w = tid >> 6, lane = tid & 63;
    const int g = lane >> 4, c = lane & 15;
    const size_t rowBase = (size_t)b * 4096;
    const unsigned short* VtS = Vt + (size_t)s * 65536;

#pragma unroll
    for (int rt = 0; rt < 2; rt++)
#pragma unroll
        for (int ks = 0; ks < 2; ks++) {
            int token = m + 4 * (qt * 128 + w * 32 + rt * 16 + c);
            async_copy16(Qg + (rowBase + token) * 1024 + h * 64 + ks * 32 + g * 8,
                         Qs + ((w * 2 + rt) * 2 + ks) * 512);
        }

    floatx4 oacc[2][4];
#pragma unroll
    for (int rt = 0; rt < 2; rt++)
#pragma unroll
        for (int dt = 0; dt < 4; dt++) oacc[rt][dt] = (floatx4){0.f, 0.f, 0.f, 0.f};
    float lsum[2] = {0.f, 0.f};

    for (int kt = 0; kt < 16; ++kt) {
        __syncthreads();
#pragma unroll
        for (int ks = 0; ks < 2; ks++) {
            int token = m + 4 * (kt * 64 + w * 16 + c);
            async_copy16(Kg + (rowBase + token) * 1024 + h * 64 + ks * 32 + g * 8,
                         Ks + (w * 2 + ks) * 512);
        }
#pragma unroll
        for (int kc = 0; kc < 2; kc++) {
            async_copy16(VtS + (size_t)(w * 16 + c) * 1024 + kt * 64 + kc * 32 + g * 8,
                         Vs + (w * 2 + kc) * 512);
        }
        __syncthreads();

        floatx4 sacc[4][2];
#pragma unroll
        for (int k4 = 0; k4 < 4; k4++)
#pragma unroll
            for (int rt = 0; rt < 2; rt++) sacc[k4][rt] = (floatx4){0.f, 0.f, 0.f, 0.f};
#pragma unroll
        for (int ks = 0; ks < 2; ks++) {
            short8 kf[4], qf[2];
#pragma unroll
            for (int k4 = 0; k4 < 4; k4++)
                kf[k4] = *(const short8*)(Ks + (((k4 * 2 + ks) * 4 + g) * 16 + c) * 8);
#pragma unroll
            for (int rt = 0; rt < 2; rt++)
                qf[rt] = *(const short8*)(Qs + ((((w * 2 + rt) * 2 + ks) * 4 + g) * 16 + c) * 8);
#pragma unroll
            for (int k4 = 0; k4 < 4; k4++)
#pragma unroll
                for (int rt = 0; rt < 2; rt++)
                    sacc[k4][rt] = __builtin_amdgcn_mfma_f32_16x16x32_bf16(kf[k4], qf[rt], sacc[k4][rt], 0, 0, 0);
        }

#pragma unroll
        for (int k4 = 0; k4 < 4; k4++) {
            const int kc = k4 >> 1;
            const int gr = (k4 & 1) * 2 + (g >> 1);
            const int j0 = (g & 1) * 4;
#pragma unroll
            for (int rt = 0; rt < 2; rt++) {
                float e0 = __builtin_amdgcn_exp2f(sacc[k4][rt][0]);
                float e1 = __builtin_amdgcn_exp2f(sacc[k4][rt][1]);
                float e2 = __builtin_amdgcn_exp2f(sacc[k4][rt][2]);
                float e3 = __builtin_amdgcn_exp2f(sacc[k4][rt][3]);
                lsum[rt] += (e0 + e1) + (e2 + e3);
                uint2 pk;
                pk.x = pack2bf(e0, e1);
                pk.y = pack2bf(e2, e3);
                *(uint2*)(Ps + w * 2048 + (((rt * 2 + kc) * 4 + gr) * 16 + c) * 8 + j0) = pk;
            }
        }

#pragma unroll
        for (int kc = 0; kc < 2; kc++) {
            short8 pf[2], vf[4];
#pragma unroll
            for (int rt = 0; rt < 2; rt++)
                pf[rt] = *(const short8*)(Ps + w * 2048 + (((rt * 2 + kc) * 4 + g) * 16 + c) * 8);
#pragma unroll
            for (int dt = 0; dt < 4; dt++)
                vf[dt] = *(const short8*)(Vs + (((dt * 2 + kc) * 4 + g) * 16 + c) * 8);
#pragma unroll
            for (int rt = 0; rt < 2; rt++)
#pragma unroll
                for (int dt = 0; dt < 4; dt++)
                    oacc[rt][dt] = __builtin_amdgcn_mfma_f32_16x16x32_bf16(pf[rt], vf[dt], oacc[rt][dt], 0, 0, 0);
        }
    }

#pragma unroll
    for (int rt = 0; rt < 2; rt++) {
        float l = lsum[rt];
        l += __shfl_xor(l, 16, 64);
        l += __shfl_xor(l, 32, 64);
        if (lane < 16) als[w * 32 + rt * 16 + c] = 1.0f / l;
    }
    float4 li[2];
#pragma unroll
    for (int rt = 0; rt < 2; rt++) li[rt] = *(float4*)(&als[w * 32 + rt * 16 + g * 4]);

#pragma unroll
    for (int rt = 0; rt < 2; rt++) {
#pragma unroll
        for (int r = 0; r < 4; r++) {
            float inv = (r == 0) ? li[rt].x : (r == 1) ? li[rt].y : (r == 2) ? li[rt].z : li[rt].w;
            int token = m + 4 * (qt * 128 + w * 32 + rt * 16 + g * 4 + r);
            size_t rowOff = (rowBase + token) * 1024 + h * 64;
#pragma unroll
            for (int dt = 0; dt < 4; dt++)
                Og[rowOff + dt * 16 + c] = f2b(oacc[rt][dt][r] * inv);
        }
    }
}

extern "C" void kernel_launch(void* const* d_in, const int* in_sizes, int n_in,
                              void* d_out, int out_size, void* d_ws, size_t ws_size,
                              hipStream_t stream) {
    const float* x  = (const float*)d_in[0];
    const float* Wq = (const float*)d_in[1];
    const float* bq = (const float*)d_in[2];
    const float* Wk = (const float*)d_in[3];
    const float* bk = (const float*)d_in[4];
    const float* Wv = (const float*)d_in[5];
    const float* bv = (const float*)d_in[6];
    const float* Wo = (const float*)d_in[7];
    const float* bo = (const float*)d_in[8];

    const float SC = 0.18033688011112042f;  // (1/8) * log2(e), folded into Wq/bq

    char* ws = (char*)d_ws;
    const size_t SZ = 33554432;  // 32 MB = 16M bf16
    unsigned short* xb  = (unsigned short*)(ws);          // dead after QKV gemm
    unsigned short* Vtp = (unsigned short*)(ws);          // reuses xb region
    unsigned short* qb  = (unsigned short*)(ws + SZ);     // q,k,v contiguous
    unsigned short* ob  = (unsigned short*)(ws + 4 * SZ);
    unsigned short* Wt3 = (unsigned short*)(ws + 5 * SZ);
    unsigned short* Wot = Wt3 + 3ull * 1024 * 1024;

    cvt_kernel<<<16384, 256, 0, stream>>>(x, xb, 4194304);
    cvt_w_t<<<dim3(16, 16, 4), 256, 0, stream>>>(Wq, Wk, Wv, Wo, Wt3, Wot, SC);
    gemm_k<false><<<1536, 256, 0, stream>>>(xb, Wt3, bq, bk, bv, qb, SC);
    vtrans<<<dim3(16, 256), 256, 0, stream>>>(qb + 2ull * 16777216ull, Vtp);
    attn_k<<<2048, 256, 0, stream>>>(qb, qb + 16777216ull, Vtp, ob);
    gemm_k<true><<<512, 256, 0, stream>>>(ob, Wot, bo, bo, bo, d_out, 1.0f);
}

// Round 7
// 391.659 us; speedup vs baseline: 1.3701x; 1.0514x over previous
//
#include <hip/hip_runtime.h>
#include <hip/hip_bf16.h>

// B=4, L=4096, D=1024, H=16, M=4, dk=64, n=1024. All-bf16 MFMA pipeline.
// R7: attn VALU diet — Q frags in regs (no Qs LDS, 4 blocks/CU), l via
// ones-column MFMA (no lsum adds, no epilogue reduce), v_perm_b32 bf16 pack
// (3 instr vs 6), strength-reduced staging pointers. R6 attn was VALU-bound:
// 58% VALUBusy vs 24% MfmaUtil.

typedef __attribute__((ext_vector_type(8))) short short8;
typedef __attribute__((ext_vector_type(8))) unsigned short ushort8v;
typedef __attribute__((ext_vector_type(4))) float floatx4;

__device__ __forceinline__ float b2f(unsigned short h) {
    union { unsigned int u; float f; } v; v.u = ((unsigned int)h) << 16; return v.f;
}
__device__ __forceinline__ unsigned short f2b(float f) {
    union { float f; unsigned int u; } v; v.f = f;
    unsigned int r = v.u + 0x7fffu + ((v.u >> 16) & 1u);
    return (unsigned short)(r >> 16);
}
__device__ __forceinline__ unsigned int fbits(float f) {
    union { float f; unsigned int u; } v; v.f = f; return v.u;
}
__device__ __forceinline__ void async_copy16(const unsigned short* g, unsigned short* l) {
    __builtin_amdgcn_global_load_lds((const __attribute__((address_space(1))) void*)g,
                                     (__attribute__((address_space(3))) void*)l, 16, 0, 0);
}

// ---------------- fp32 -> bf16 convert (x) ----------------
__global__ __launch_bounds__(256)
void cvt_kernel(const float* __restrict__ in, unsigned short* __restrict__ out, int n4) {
    int i = blockIdx.x * 256 + threadIdx.x;
    if (i >= n4) return;
    float4 v = ((const float4*)in)[i];
    ushort4 o;
    o.x = f2b(v.x); o.y = f2b(v.y); o.z = f2b(v.z); o.w = f2b(v.w);
    ((ushort4*)out)[i] = o;
}

// ---------------- W [K][N] fp32 -> Wt [N][K] bf16, all 4 weights in one grid ----------------
__global__ __launch_bounds__(256)
void cvt_w_t(const float* __restrict__ Wq, const float* __restrict__ Wk,
             const float* __restrict__ Wv, const float* __restrict__ Wo,
             unsigned short* __restrict__ Wt3, unsigned short* __restrict__ Wot, float s0) {
    __shared__ float tile[64][65];
    const int kt = blockIdx.x, nt = blockIdx.y, z = blockIdx.z;
    const float* W = (z == 0) ? Wq : (z == 1) ? Wk : (z == 2) ? Wv : Wo;
    unsigned short* Wt = (z < 3) ? (Wt3 + (size_t)z * 1048576) : Wot;
    const float sc = (z == 0) ? s0 : 1.0f;
    const int t = threadIdx.x;
    const int r = t >> 2, cg = t & 3;
    const float* src = W + (size_t)(kt * 64 + r) * 1024 + nt * 64 + cg * 16;
#pragma unroll
    for (int j = 0; j < 4; j++) {
        float4 v = *(const float4*)(src + j * 4);
        tile[r][cg * 16 + j * 4 + 0] = v.x;
        tile[r][cg * 16 + j * 4 + 1] = v.y;
        tile[r][cg * 16 + j * 4 + 2] = v.z;
        tile[r][cg * 16 + j * 4 + 3] = v.w;
    }
    __syncthreads();
    unsigned short* dst = Wt + (size_t)(nt * 64 + r) * 1024 + kt * 64 + cg * 16;
    ushort8v o0, o1;
#pragma unroll
    for (int j = 0; j < 8; j++) o0[j] = f2b(tile[cg * 16 + j][r] * sc);
#pragma unroll
    for (int j = 0; j < 8; j++) o1[j] = f2b(tile[cg * 16 + 8 + j][r] * sc);
    *(ushort8v*)(dst) = o0;
    *(ushort8v*)(dst + 8) = o1;
}

// ---------------- GEMM: C[M][N] = A[M][K] * Bt[N][K]^T + bias*bs ----------------
// BM=256, BN=128, BK=64; 4 waves (2x2), 8x4 accum/wave = 64 MFMA per K-iter.
// LDS XOR swizzle: chunk(row,kc) @ elem (row*8 + (kc^(row&7)))*8.
// Grid 512*nz: xcd=id&7, q=id>>3, tileM=xcd*8+(q&7), rz=q>>3, tileN=rz&7, z=rz>>3.
template <bool F32OUT>
__global__ __launch_bounds__(256, 2)
void gemm_k(const unsigned short* __restrict__ A,
            const unsigned short* __restrict__ BtBase,
            const float* __restrict__ bias0,
            const float* __restrict__ bias1,
            const float* __restrict__ bias2,
            void* __restrict__ OutBase, float s0) {
    constexpr int K = 1024, N = 1024;
    __shared__ __align__(16) unsigned short As[256 * 64];
    __shared__ __align__(16) unsigned short Bs[128 * 64];
    const int id = blockIdx.x;
    const int xcd = id & 7;
    const int q = id >> 3;
    const int tileM = xcd * 8 + (q & 7);
    const int rz = q >> 3;
    const int tileN = rz & 7;
    const int z = rz >> 3;
    const unsigned short* Bt = BtBase + (size_t)z * (1024 * 1024);
    const float* bias = (z == 0) ? bias0 : (z == 1 ? bias1 : bias2);
    const float bs = (z == 0) ? s0 : 1.0f;
    const int tid = threadIdx.x, w = tid >> 6, lane = tid & 63;
    const int wr = w >> 1, wc = w & 1;
    const int g = lane >> 4, c = lane & 15;
    const int c7 = c & 7;
    const int r8 = lane >> 3, j8 = lane & 7;
    const int kcs = (j8 ^ r8) * 8;   // swizzled k-chunk this lane stages

    floatx4 acc[8][4];
#pragma unroll
    for (int i = 0; i < 8; i++)
#pragma unroll
        for (int jj = 0; jj < 4; jj++) acc[i][jj] = (floatx4){0.f, 0.f, 0.f, 0.f};

    for (int kt = 0; kt < K / 64; ++kt) {
        __syncthreads();
#pragma unroll
        for (int t = 0; t < 8; t++) {          // A: 32 segs of 8 rows
            int seg = w * 8 + t;
            int rowA = tileM * 256 + seg * 8 + r8;
            async_copy16(A + (size_t)rowA * K + kt * 64 + kcs, As + seg * 512);
        }
#pragma unroll
        for (int t = 0; t < 4; t++) {          // B: 16 segs of 8 rows
            int seg = w * 4 + t;
            int rowB = tileN * 128 + seg * 8 + r8;
            async_copy16(Bt + (size_t)rowB * K + kt * 64 + kcs, Bs + seg * 512);
        }
        __syncthreads();
#pragma unroll
        for (int ks = 0; ks < 2; ks++) {
            const int kx = ((ks * 4 + g) ^ c7) * 8;
            short8 bf[4];
#pragma unroll
            for (int ct = 0; ct < 4; ct++)
                bf[ct] = *(const short8*)(Bs + (wc * 64 + ct * 16 + c) * 64 + kx);
#pragma unroll
            for (int rt = 0; rt < 8; rt++) {
                short8 af = *(const short8*)(As + (wr * 128 + rt * 16 + c) * 64 + kx);
#pragma unroll
                for (int ct = 0; ct < 4; ct++)
                    acc[rt][ct] = __builtin_amdgcn_mfma_f32_16x16x32_bf16(af, bf[ct], acc[rt][ct], 0, 0, 0);
            }
        }
    }
#pragma unroll
    for (int ct = 0; ct < 4; ct++) {
        int col = tileN * 128 + wc * 64 + ct * 16 + c;
        float bvv = bias[col] * bs;
#pragma unroll
        for (int rt = 0; rt < 8; rt++) {
            int row0 = tileM * 256 + wr * 128 + rt * 16 + g * 4;
#pragma unroll
            for (int r = 0; r < 4; r++) {
                float v = acc[rt][ct][r] + bvv;
                if (F32OUT) {
                    ((float*)OutBase)[(size_t)(row0 + r) * N + col] = v;
                } else {
                    ((unsigned short*)OutBase)[(size_t)z * (16384ull * 1024ull) +
                                               (size_t)(row0 + r) * N + col] = f2b(v);
                }
            }
        }
    }
}

// ---------------- V transpose: v[B,L,D] -> Vt[slice=(b,h,m)][d=64][i=1024] ----------------
__global__ __launch_bounds__(256)
void vtrans(const unsigned short* __restrict__ V, unsigned short* __restrict__ Vt) {
    __shared__ unsigned short tile[64 * 72];
    const int it = blockIdx.x, s = blockIdx.y;
    const int m = s & 3, h = (s >> 2) & 15, b = s >> 6;
    const int tid = threadIdx.x;
    {
        int il = tid >> 2, cg = tid & 3;
        const unsigned short* gsrc =
            V + ((size_t)b * 4096 + m + 4 * (it * 64 + il)) * 1024 + h * 64 + cg * 16;
        *(ushort8v*)(tile + il * 72 + cg * 16) = *(const ushort8v*)gsrc;
        *(ushort8v*)(tile + il * 72 + cg * 16 + 8) = *(const ushort8v*)(gsrc + 8);
    }
    __syncthreads();
    {
        int dl = tid >> 2, ig = (tid & 3) * 16;
        ushort8v o0, o1;
#pragma unroll
        for (int j = 0; j < 8; j++) o0[j] = tile[(ig + j) * 72 + dl];
#pragma unroll
        for (int j = 0; j < 8; j++) o1[j] = tile[(ig + 8 + j) * 72 + dl];
        unsigned short* dst = Vt + (size_t)s * 65536 + (size_t)dl * 1024 + it * 64 + ig;
        *(ushort8v*)dst = o0;
        *(ushort8v*)(dst + 8) = o1;
    }
}

// ---------------- Attention ----------------
// 1-D grid 2048 blocks; decode xcd=id&7, q=id>>3, s=xcd*32+(q>>3), qt=q&7.
// Q frags live in registers (loaded once). S^T = K·Q^T; p=exp2(s) (scale folded
// into Wq); P packed to bf16 via v_perm_b32 into per-wave LDS; O = P·V with an
// extra all-ones B-frag MFMA accumulating l per-row in oacc-matched layout.
__global__ __launch_bounds__(256, 4)
void attn_k(const unsigned short* __restrict__ Qg,
            const unsigned short* __restrict__ Kg,
            const unsigned short* __restrict__ Vt,
            unsigned short* __restrict__ Og) {
    __shared__ __align__(16) unsigned short Ks[64 * 64];    // [kt4][ks][g][c][8]
    __shared__ __align__(16) unsigned short Vs[64 * 64];    // [dt][kc][g][c][8]
    __shared__ __align__(16) unsigned short Ps[4 * 2048];   // per-wave [rt*2+kc][g][c][8]

    const int id = blockIdx.x;
    const int xcd = id & 7;
    const int qq = id >> 3;
    const int s = xcd * 32 + (qq >> 3);
    const int qt = qq & 7;
    const int m = s & 3, h = (s >> 2) & 15, b = s >> 6;
    const int tid = threadIdx.x, w = tid >> 6, lane = tid & 63;
    const int g = lane >> 4, c = lane & 15;
    const size_t rowBase = (size_t)b * 4096;

    // Q fragments straight to registers (read-once data; 16B/lane)
    short8 qf[2][2];
#pragma unroll
    for (int rt = 0; rt < 2; rt++)
#pragma unroll
        for (int ks = 0; ks < 2; ks++)
            qf[rt][ks] = *(const short8*)(Qg +
                (rowBase + (size_t)(m + 4 * (qt * 128 + w * 32 + rt * 16 + c))) * 1024 +
                h * 64 + ks * 32 + g * 8);

    // strength-reduced staging pointers
    const unsigned short* kPtr =
        Kg + (rowBase + (size_t)(m + 4 * (w * 16 + c))) * 1024 + h * 64 + g * 8;
    const unsigned short* vPtr =
        Vt + (size_t)s * 65536 + (size_t)(w * 16 + c) * 1024 + g * 8;

    // all-ones B-fragment: l-column trick
    short8 ones;
#pragma unroll
    for (int j = 0; j < 8; j++) ones[j] = (short)0x3F80;   // bf16 1.0

    floatx4 oacc[2][4], lacc[2];
#pragma unroll
    for (int rt = 0; rt < 2; rt++) {
        lacc[rt] = (floatx4){0.f, 0.f, 0.f, 0.f};
#pragma unroll
        for (int dt = 0; dt < 4; dt++) oacc[rt][dt] = (floatx4){0.f, 0.f, 0.f, 0.f};
    }

    for (int kt = 0; kt < 16; ++kt) {
        __syncthreads();
        async_copy16(kPtr,      Ks + (w * 2 + 0) * 512);
        async_copy16(kPtr + 32, Ks + (w * 2 + 1) * 512);
        async_copy16(vPtr,      Vs + (w * 2 + 0) * 512);
        async_copy16(vPtr + 32, Vs + (w * 2 + 1) * 512);
        kPtr += 262144;   // 256 tokens * 1024 elems
        vPtr += 64;       // 64 keys along i-dim
        __syncthreads();

        // S^T[key][q] = K·Q^T : A=K (4 key-tiles), B=Q (2 q-tiles, regs)
        floatx4 sacc[4][2];
#pragma unroll
        for (int k4 = 0; k4 < 4; k4++)
#pragma unroll
            for (int rt = 0; rt < 2; rt++) sacc[k4][rt] = (floatx4){0.f, 0.f, 0.f, 0.f};
#pragma unroll
        for (int ks = 0; ks < 2; ks++) {
            short8 kf[4];
#pragma unroll
            for (int k4 = 0; k4 < 4; k4++)
                kf[k4] = *(const short8*)(Ks + (((k4 * 2 + ks) * 4 + g) * 16 + c) * 8);
#pragma unroll
            for (int k4 = 0; k4 < 4; k4++)
#pragma unroll
                for (int rt = 0; rt < 2; rt++)
                    sacc[k4][rt] = __builtin_amdgcn_mfma_f32_16x16x32_bf16(kf[k4], qf[rt][ks], sacc[k4][rt], 0, 0, 0);
        }

        // p = exp2(s), pack pairs via v_perm_b32, write b64 to per-wave Ps
#pragma unroll
        for (int k4 = 0; k4 < 4; k4++) {
            const int kc = k4 >> 1;
            const int gr = (k4 & 1) * 2 + (g >> 1);
            const int j0 = (g & 1) * 4;
#pragma unroll
            for (int rt = 0; rt < 2; rt++) {
                unsigned int u0 = fbits(__builtin_amdgcn_exp2f(sacc[k4][rt][0])) + 0x8000u;
                unsigned int u1 = fbits(__builtin_amdgcn_exp2f(sacc[k4][rt][1])) + 0x8000u;
                unsigned int u2 = fbits(__builtin_amdgcn_exp2f(sacc[k4][rt][2])) + 0x8000u;
                unsigned int u3 = fbits(__builtin_amdgcn_exp2f(sacc[k4][rt][3])) + 0x8000u;
                uint2 pk;
                pk.x = __builtin_amdgcn_perm(u1, u0, 0x07060302u);  // [e1.hi16 : e0.hi16]
                pk.y = __builtin_amdgcn_perm(u3, u2, 0x07060302u);
                *(uint2*)(Ps + w * 2048 + (((rt * 2 + kc) * 4 + gr) * 16 + c) * 8 + j0) = pk;
            }
        }

        // O += P·V ; l += P·1  (ones B-frag -> l lands oacc-aligned per row)
#pragma unroll
        for (int kc = 0; kc < 2; kc++) {
            short8 pf[2], vf[4];
#pragma unroll
            for (int rt = 0; rt < 2; rt++)
                pf[rt] = *(const short8*)(Ps + w * 2048 + (((rt * 2 + kc) * 4 + g) * 16 + c) * 8);
#pragma unroll
            for (int dt = 0; dt < 4; dt++)
                vf[dt] = *(const short8*)(Vs + (((dt * 2 + kc) * 4 + g) * 16 + c) * 8);
#pragma unroll
            for (int rt = 0; rt < 2; rt++) {
                lacc[rt] = __builtin_amdgcn_mfma_f32_16x16x32_bf16(pf[rt], ones, lacc[rt], 0, 0, 0);
#pragma unroll
                for (int dt = 0; dt < 4; dt++)
                    oacc[rt][dt] = __builtin_amdgcn_mfma_f32_16x16x32_bf16(pf[rt], vf[dt], oacc[rt][dt], 0, 0, 0);
            }
        }
    }

    // epilogue: l is already per-row in matching slots; normalize and scatter
#pragma unroll
    for (int rt = 0; rt < 2; rt++) {
#pragma unroll
        for (int r = 0; r < 4; r++) {
            float inv = 1.0f / lacc[rt][r];
            int token = m + 4 * (qt * 128 + w * 32 + rt * 16 + g * 4 + r);
            size_t rowOff = (rowBase + token) * 1024 + h * 64;
#pragma unroll
            for (int dt = 0; dt < 4; dt++)
                Og[rowOff + dt * 16 + c] = f2b(oacc[rt][dt][r] * inv);
        }
    }
}

extern "C" void kernel_launch(void* const* d_in, const int* in_sizes, int n_in,
                              void* d_out, int out_size, void* d_ws, size_t ws_size,
                              hipStream_t stream) {
    const float* x  = (const float*)d_in[0];
    const float* Wq = (const float*)d_in[1];
    const float* bq = (const float*)d_in[2];
    const float* Wk = (const float*)d_in[3];
    const float* bk = (const float*)d_in[4];
    const float* Wv = (const float*)d_in[5];
    const float* bv = (const float*)d_in[6];
    const float* Wo = (const float*)d_in[7];
    const float* bo = (const float*)d_in[8];

    const float SC = 0.18033688011112042f;  // (1/8) * log2(e), folded into Wq/bq

    char* ws = (char*)d_ws;
    const size_t SZ = 33554432;  // 32 MB = 16M bf16
    unsigned short* xb  = (unsigned short*)(ws);          // dead after QKV gemm
    unsigned short* Vtp = (unsigned short*)(ws);          // reuses xb region
    unsigned short* qb  = (unsigned short*)(ws + SZ);     // q,k,v contiguous
    unsigned short* ob  = (unsigned short*)(ws + 4 * SZ);
    unsigned short* Wt3 = (unsigned short*)(ws + 5 * SZ);
    unsigned short* Wot = Wt3 + 3ull * 1024 * 1024;

    cvt_kernel<<<16384, 256, 0, stream>>>(x, xb, 4194304);
    cvt_w_t<<<dim3(16, 16, 4), 256, 0, stream>>>(Wq, Wk, Wv, Wo, Wt3, Wot, SC);
    gemm_k<false><<<1536, 256, 0, stream>>>(xb, Wt3, bq, bk, bv, qb, SC);
    vtrans<<<dim3(16, 256), 256, 0, stream>>>(qb + 2ull * 16777216ull, Vtp);
    attn_k<<<2048, 256, 0, stream>>>(qb, qb + 16777216ull, Vtp, ob);
    gemm_k<true><<<512, 256, 0, stream>>>(ob, Wot, bo, bo, bo, d_out, 1.0f);
}